// Round 13
// baseline (1154.472 us; speedup 1.0000x reference)
//
#include <hip/hip_runtime.h>
#include <hip/hip_bf16.h>
#include <stdint.h>

#define NN 8192
#define IN_DIM 343
#define IN_PAD 352
#define HID 1000
#define HID_PAD 1024
#define EPS 1e-5f
#define BK2 64            // GEMM2 K-step

typedef __attribute__((ext_vector_type(8))) short bf16x8;
typedef __attribute__((ext_vector_type(4))) float f32x4;

static __device__ __forceinline__ unsigned short f2bf(float f) {
    union { float f; unsigned int u; } v; v.f = f;
    unsigned int u = v.u;
    unsigned int r = (u + 0x7FFFu + ((u >> 16) & 1u)) >> 16;   // RNE
    return (unsigned short)r;
}

static __device__ __forceinline__ unsigned cvt_pk_bf16(float lo, float hi) {
    unsigned r;
    asm("v_cvt_pk_bf16_f32 %0, %1, %2" : "=v"(r) : "v"(lo), "v"(hi));
    return r;
}

// ---------------- conversion kernels ----------------

__global__ __launch_bounds__(256) void k_cvt_feat(const float* __restrict__ src,
                                                  unsigned short* __restrict__ dst) {
    int idx = blockIdx.x * blockDim.x + threadIdx.x;
    if (idx >= NN * IN_PAD) return;
    int row = idx / IN_PAD;
    int col = idx - row * IN_PAD;
    dst[idx] = (col < IN_DIM) ? f2bf(src[(size_t)row * IN_DIM + col]) : 0;
}

__global__ __launch_bounds__(256) void k_cvt_w1t(const float* __restrict__ W1,
                                                 unsigned short* __restrict__ dst) {
    int idx = blockIdx.x * blockDim.x + threadIdx.x;
    if (idx >= HID_PAD * IN_PAD) return;
    int n = idx / IN_PAD;
    int k = idx - n * IN_PAD;
    dst[idx] = (k < IN_DIM && n < HID) ? f2bf(W1[(size_t)k * HID + n]) : 0;
}

// ---------------- GEMM1: bf16 128x128 tile (m97 2-barrier structure) ----------------

__global__ void k_gemm_bf(const unsigned short* __restrict__ A,
                          const unsigned short* __restrict__ Bt,
                          unsigned short* __restrict__ Cout,
                          int M, int N, int K) {
    __shared__ unsigned short ldsA[128 * 32];
    __shared__ unsigned short ldsB[128 * 32];

    const int tid = threadIdx.x;
    const int nbn = N >> 7;
    const int bm = blockIdx.x / nbn;
    const int bn = blockIdx.x - bm * nbn;

    const int wid = tid >> 6, lane = tid & 63;
    const int wr = wid >> 1, wc = wid & 1;
    const int lr = lane & 15, lg = lane >> 4;

    f32x4 acc[4][4] = {};

    const int r0 = tid >> 2, s0 = tid & 3;
    const unsigned short* Ag0 = A + ((size_t)bm * 128 + r0) * K + s0 * 8;
    const unsigned short* Ag1 = A + ((size_t)bm * 128 + 64 + r0) * K + s0 * 8;
    const unsigned short* Bg0 = Bt + ((size_t)bn * 128 + r0) * K + s0 * 8;
    const unsigned short* Bg1 = Bt + ((size_t)bn * 128 + 64 + r0) * K + s0 * 8;
    unsigned short* lA0 = ldsA + (size_t)(wid * 64) * 8;
    unsigned short* lA1 = ldsA + (size_t)(256 + wid * 64) * 8;
    unsigned short* lB0 = ldsB + (size_t)(wid * 64) * 8;
    unsigned short* lB1 = ldsB + (size_t)(256 + wid * 64) * 8;

    for (int kt = 0; kt < K; kt += 32) {
        __builtin_amdgcn_global_load_lds(
            (const __attribute__((address_space(1))) void*)(Ag0 + kt),
            (__attribute__((address_space(3))) void*)lA0, 16, 0, 0);
        __builtin_amdgcn_global_load_lds(
            (const __attribute__((address_space(1))) void*)(Ag1 + kt),
            (__attribute__((address_space(3))) void*)lA1, 16, 0, 0);
        __builtin_amdgcn_global_load_lds(
            (const __attribute__((address_space(1))) void*)(Bg0 + kt),
            (__attribute__((address_space(3))) void*)lB0, 16, 0, 0);
        __builtin_amdgcn_global_load_lds(
            (const __attribute__((address_space(1))) void*)(Bg1 + kt),
            (__attribute__((address_space(3))) void*)lB1, 16, 0, 0);
        __syncthreads();

        bf16x8 af[4], bfr[4];
#pragma unroll
        for (int i = 0; i < 4; i++) {
            af[i]  = *(const bf16x8*)&ldsA[((wr * 64 + i * 16 + lr) * 32) + lg * 8];
            bfr[i] = *(const bf16x8*)&ldsB[((wc * 64 + i * 16 + lr) * 32) + lg * 8];
        }
#pragma unroll
        for (int i = 0; i < 4; i++)
#pragma unroll
            for (int j = 0; j < 4; j++)
                acc[i][j] = __builtin_amdgcn_mfma_f32_16x16x32_bf16(af[i], bfr[j], acc[i][j], 0, 0, 0);
        __syncthreads();
    }

    const int row0 = bm * 128 + wr * 64;
    const int col0 = bn * 128 + wc * 64;
#pragma unroll
    for (int mi = 0; mi < 4; mi++) {
#pragma unroll
        for (int ni = 0; ni < 4; ni++) {
            int col = col0 + ni * 16 + lr;
#pragma unroll
            for (int j = 0; j < 4; j++) {
                int row = row0 + mi * 16 + lg * 4 + j;
                Cout[(size_t)row * N + col] = f2bf(acc[mi][ni][j]);
            }
        }
    }
}

// ---------------- GEMM2: bf16-A-in-LDS (reg-staged cvt), dbuf B, BK=64 ----------------
// h1 = relu(adj_fp32 * xwt^T + b1). 128x128 tile, 4 waves, 48 KB LDS -> 3 blocks/CU.
// A: global fp32 -> regs (1 body ahead) -> cvt_pk -> ds_write_b64 into [128][64] bf16
//    (XOR swizzle slot^= r&7; write sub-slot u' = row128B-contig, conflict-free).
// B: global_load_lds into double-buffered [128][64] bf16 (issued 2 tiles ahead).
// No manual vmcnt: the ds_write's register dependency makes the compiler emit a
// COUNTED vmcnt (B/A of t+2 issued before it stay in flight). lgkmcnt(0) + raw
// s_barrier; never a full drain in the main loop.
// LDS reads/wave/iter: 8 A + 8 B (b128) vs R12's 24 — the R12 LDS-pipe limit.

#define G2_BODY(PAR, AR_W, AR_L, KT)                                                        \
  {                                                                                         \
    _Pragma("unroll")                                                                       \
    for (int kk = 0; kk < 2; kk++) {                                                        \
      bf16x8 af[4], bfr[4];                                                                 \
      _Pragma("unroll")                                                                     \
      for (int i = 0; i < 4; i++) {                                                         \
        const int r = wr * 64 + i * 16 + lr;                                                \
        const int p = (kk * 4 + lg) ^ (r & 7);                                              \
        af[i] = *(const bf16x8*)&ldsA[r * 64 + p * 8];                                      \
      }                                                                                     \
      _Pragma("unroll")                                                                     \
      for (int j = 0; j < 4; j++) {                                                         \
        const int r = wc * 64 + j * 16 + lr;                                                \
        const int p = (kk * 4 + lg) ^ (r & 7);                                              \
        bfr[j] = *(const bf16x8*)&ldsB[PAR][r * 64 + p * 8];                                \
      }                                                                                     \
      __builtin_amdgcn_s_setprio(1);                                                        \
      _Pragma("unroll")                                                                     \
      for (int i = 0; i < 4; i++)                                                           \
        _Pragma("unroll")                                                                   \
        for (int j = 0; j < 4; j++)                                                         \
          acc[i][j] = __builtin_amdgcn_mfma_f32_16x16x32_bf16(af[i], bfr[j], acc[i][j], 0, 0, 0); \
      __builtin_amdgcn_s_setprio(0);                                                        \
    }                                                                                       \
    __builtin_amdgcn_s_barrier();                                                           \
    __builtin_amdgcn_sched_barrier(0);                                                      \
    if ((KT) + 64 < NN) {                                                                   \
      if ((KT) + 128 < NN) {                                                                \
        _Pragma("unroll")                                                                   \
        for (int q = 0; q < 4; q++) {                                                       \
          const int c = wid * 4 + q;                                                        \
          const int r = c * 8 + (lane >> 3);                                                \
          __builtin_amdgcn_global_load_lds(                                                 \
              (const __attribute__((address_space(1))) void*)                               \
                  (Bbase + (size_t)r * NN + (KT) + 128 + bslot * 8),                        \
              (__attribute__((address_space(3))) void*)(&ldsB[PAR][0] + c * 512),           \
              16, 0, 0);                                                                    \
        }                                                                                   \
        _Pragma("unroll")                                                                   \
        for (int q = 0; q < 8; q++) {                                                       \
          const int c = wid * 8 + q;                                                        \
          AR_L[q] = *(const float4*)(Abase + (size_t)(c * 4 + (lane >> 4)) * NN             \
                                     + (KT) + 128 + (lane & 15) * 4);                       \
        }                                                                                   \
      }                                                                                     \
      _Pragma("unroll")                                                                     \
      for (int q = 0; q < 8; q++) {                                                         \
        const int c = wid * 8 + q;                                                          \
        const int r = c * 4 + (lane >> 4);                                                  \
        const int s = lane & 15;                                                            \
        uint2 pk;                                                                           \
        pk.x = cvt_pk_bf16(AR_W[q].x, AR_W[q].y);                                           \
        pk.y = cvt_pk_bf16(AR_W[q].z, AR_W[q].w);                                           \
        *(uint2*)&ldsA[r * 64 + (((s >> 1) ^ (r & 7)) << 3) + (s & 1) * 4] = pk;            \
      }                                                                                     \
      asm volatile("s_waitcnt lgkmcnt(0)" ::: "memory");                                    \
      __builtin_amdgcn_sched_barrier(0);                                                    \
    }                                                                                       \
    __builtin_amdgcn_s_barrier();                                                           \
    __builtin_amdgcn_sched_barrier(0);                                                      \
  }

__global__ __launch_bounds__(256, 3) void k_gemm2(const float* __restrict__ A,
                                                  const unsigned short* __restrict__ Bt,
                                                  const float* __restrict__ b1,
                                                  float* __restrict__ H) {
    __shared__ unsigned short ldsA[128 * BK2];        // 16 KB bf16 A
    __shared__ unsigned short ldsB[2][128 * BK2];     // 2 x 16 KB bf16 B

    const int tid = threadIdx.x;
    const int wg = blockIdx.x;                   // 512 blocks = 64 bm x 8 bn
    const int swz = (wg & 7) * 64 + (wg >> 3);   // bijective; XCD x owns bm in [8x,8x+8)
    const int bm = swz >> 3;
    const int bn = swz & 7;

    const int wid = tid >> 6, lane = tid & 63;
    const int wr = wid >> 1, wc = wid & 1;
    const int lr = lane & 15, lg = lane >> 4;

    f32x4 acc[4][4] = {};

    const float* Abase = A + ((size_t)bm * 128) * NN;
    const unsigned short* Bbase = Bt + ((size_t)bn * 128) * NN;

    const int bslot = (lane & 7) ^ (lane >> 3);      // B swizzle: row&7 = lane>>3

    float4 arA[8], arB[8];

    // ---- prologue: tile0 -> ldsA (via arB); B(0)->ldsB[0], B(64)->ldsB[1]; A(64)->arA
#pragma unroll
    for (int q = 0; q < 8; q++) {
        const int c = wid * 8 + q;
        arB[q] = *(const float4*)(Abase + (size_t)(c * 4 + (lane >> 4)) * NN + (lane & 15) * 4);
    }
#pragma unroll
    for (int q = 0; q < 8; q++) {
        const int c = wid * 8 + q;
        const int r = c * 4 + (lane >> 4);
        const int s = lane & 15;
        uint2 pk;
        pk.x = cvt_pk_bf16(arB[q].x, arB[q].y);
        pk.y = cvt_pk_bf16(arB[q].z, arB[q].w);
        *(uint2*)&ldsA[r * 64 + (((s >> 1) ^ (r & 7)) << 3) + (s & 1) * 4] = pk;
    }
#pragma unroll
    for (int buf = 0; buf < 2; buf++) {
#pragma unroll
        for (int q = 0; q < 4; q++) {
            const int c = wid * 4 + q;
            const int r = c * 8 + (lane >> 3);
            __builtin_amdgcn_global_load_lds(
                (const __attribute__((address_space(1))) void*)
                    (Bbase + (size_t)r * NN + buf * 64 + bslot * 8),
                (__attribute__((address_space(3))) void*)(&ldsB[buf][0] + c * 512),
                16, 0, 0);
        }
    }
#pragma unroll
    for (int q = 0; q < 8; q++) {
        const int c = wid * 8 + q;
        arA[q] = *(const float4*)(Abase + (size_t)(c * 4 + (lane >> 4)) * NN + 64 + (lane & 15) * 4);
    }
    asm volatile("s_waitcnt vmcnt(12) lgkmcnt(0)" ::: "memory");   // B(0) + A(0)-writes done
    __builtin_amdgcn_sched_barrier(0);
    __builtin_amdgcn_s_barrier();
    __builtin_amdgcn_sched_barrier(0);

    // ---- main loop: 128 tiles, 2 bodies per iteration (static parity / reg naming)
    for (int kt = 0; kt < NN; kt += 128) {
        G2_BODY(0, arA, arB, kt);
        G2_BODY(1, arB, arA, kt + 64);
    }

    // ---- epilogue: bias + relu fused, fp32 store
    const int row0 = bm * 128 + wr * 64;
    const int col0 = bn * 128 + wc * 64;
#pragma unroll
    for (int mi = 0; mi < 4; mi++) {
#pragma unroll
        for (int ni = 0; ni < 4; ni++) {
            int col = col0 + ni * 16 + lr;
            float b = (col < HID) ? b1[col] : 0.f;
#pragma unroll
            for (int j = 0; j < 4; j++) {
                int row = row0 + mi * 16 + lg * 4 + j;
                float v = acc[mi][ni][j] + b;
                v = v > 0.f ? v : 0.f;
                H[(size_t)row * HID_PAD + col] = v;
            }
        }
    }
}

// ---------------- LayerNorm + head ----------------
__global__ __launch_bounds__(256) void k_ln_head(const float* __restrict__ h1p,
                                                 const float* __restrict__ gamma,
                                                 const float* __restrict__ beta,
                                                 const float* __restrict__ Wm,
                                                 const float* __restrict__ bm,
                                                 float* __restrict__ out) {
    const int row = blockIdx.x;
    const int t = threadIdx.x;
    const float* hr = h1p + (size_t)row * HID_PAD;

    float v[4];
    float s = 0.f, ss = 0.f;
#pragma unroll
    for (int i = 0; i < 4; i++) {
        int ix = t + i * 256;
        float x = (ix < HID) ? hr[ix] : 0.f;
        v[i] = x; s += x; ss += x * x;
    }
#pragma unroll
    for (int o = 32; o > 0; o >>= 1) { s += __shfl_down(s, o); ss += __shfl_down(ss, o); }

    __shared__ float rs[8], rss[8];
    const int wid = t >> 6, lane = t & 63;
    if (lane == 0) { rs[wid] = s; rss[wid] = ss; }
    __syncthreads();
    if (t == 0) {
        float a = 0.f, b = 0.f;
        for (int w = 0; w < 4; w++) { a += rs[w]; b += rss[w]; }
        rs[4] = a; rss[4] = b;
    }
    __syncthreads();
    const float mean = rs[4] * (1.0f / HID);
    const float var = rss[4] * (1.0f / HID) - mean * mean;
    const float rstd = rsqrtf(var + EPS);

    float q0 = 0.f, q1 = 0.f, q2 = 0.f, q3 = 0.f;
#pragma unroll
    for (int i = 0; i < 4; i++) {
        int ix = t + i * 256;
        if (ix < HID) {
            float hn = (v[i] - mean) * rstd * gamma[ix] + beta[ix];
            const float* w = Wm + (size_t)ix * 4;
            q0 += hn * w[0]; q1 += hn * w[1]; q2 += hn * w[2]; q3 += hn * w[3];
        }
    }
#pragma unroll
    for (int o = 32; o > 0; o >>= 1) {
        q0 += __shfl_down(q0, o); q1 += __shfl_down(q1, o);
        q2 += __shfl_down(q2, o); q3 += __shfl_down(q3, o);
    }
    __shared__ float rp[4][4];
    if (lane == 0) { rp[wid][0] = q0; rp[wid][1] = q1; rp[wid][2] = q2; rp[wid][3] = q3; }
    __syncthreads();
    if (t < 4) {
        float a = rp[0][t] + rp[1][t] + rp[2][t] + rp[3][t] + bm[t];
        out[(size_t)row * 4 + t] = a;
    }
}

// ---------------- launcher ----------------
extern "C" void kernel_launch(void* const* d_in, const int* in_sizes, int n_in,
                              void* d_out, int out_size, void* d_ws, size_t ws_size,
                              hipStream_t stream) {
    const float* adj      = (const float*)d_in[0];
    const float* features = (const float*)d_in[1];
    const float* W1       = (const float*)d_in[2];
    const float* b1       = (const float*)d_in[3];
    const float* gamma    = (const float*)d_in[4];
    const float* beta     = (const float*)d_in[5];
    const float* Wm       = (const float*)d_in[6];
    const float* bm       = (const float*)d_in[7];
    float* out = (float*)d_out;

    uint8_t* ws = (uint8_t*)d_ws;
    unsigned short* feat_p = (unsigned short*)ws;                 //  5,767,168 B
    unsigned short* w1t    = (unsigned short*)(ws + 5767168);     //    720,896 B
    unsigned short* xwt    = (unsigned short*)(ws + 6488064);     // 16,777,216 B
    float*          h1     = (float*)(ws + 23265280);             // 33,554,432 B (~57 MB total)

    k_cvt_feat<<<(NN * IN_PAD + 255) / 256, 256, 0, stream>>>(features, feat_p);
    k_cvt_w1t<<<(HID_PAD * IN_PAD + 255) / 256, 256, 0, stream>>>(W1, w1t);

    // GEMM1: xwt[1024][8192] = w1t * feat_p^T  (bf16 out)
    k_gemm_bf<<<(HID_PAD / 128) * (NN / 128), 256, 0, stream>>>(
        w1t, feat_p, xwt, HID_PAD, NN, IN_PAD);

    // GEMM2: h1 = relu(adj * xwt^T + b1); bf16-A reg-staged, dbuf B, BK=64
    k_gemm2<<<(NN / 128) * (HID_PAD / 128), 256, 0, stream>>>(adj, xwt, b1, h1);

    k_ln_head<<<NN, 256, 0, stream>>>(h1, gamma, beta, Wm, bm, out);
}

// Round 14
// 260.329 us; speedup vs baseline: 4.4347x; 4.4347x over previous
//
#include <hip/hip_runtime.h>
#include <hip/hip_bf16.h>
#include <stdint.h>

#define NN 8192
#define IN_DIM 343
#define IN_PAD 352
#define HID 1000
#define HID_PAD 1024
#define EPS 1e-5f
#define BK2 64            // GEMM2 K-step
#define NT2 (NN / BK2)    // 128 K-tiles

typedef __attribute__((ext_vector_type(8))) short bf16x8;
typedef __attribute__((ext_vector_type(4))) float f32x4;

static __device__ __forceinline__ unsigned short f2bf(float f) {
    union { float f; unsigned int u; } v; v.f = f;
    unsigned int u = v.u;
    unsigned int r = (u + 0x7FFFu + ((u >> 16) & 1u)) >> 16;   // RNE
    return (unsigned short)r;
}

static __device__ __forceinline__ unsigned cvt_pk_bf16(float lo, float hi) {
    unsigned r;
    asm("v_cvt_pk_bf16_f32 %0, %1, %2" : "=v"(r) : "v"(lo), "v"(hi));
    return r;
}

// ---------------- conversion kernels ----------------

__global__ __launch_bounds__(256) void k_cvt_feat(const float* __restrict__ src,
                                                  unsigned short* __restrict__ dst) {
    int idx = blockIdx.x * blockDim.x + threadIdx.x;
    if (idx >= NN * IN_PAD) return;
    int row = idx / IN_PAD;
    int col = idx - row * IN_PAD;
    dst[idx] = (col < IN_DIM) ? f2bf(src[(size_t)row * IN_DIM + col]) : 0;
}

__global__ __launch_bounds__(256) void k_cvt_w1t(const float* __restrict__ W1,
                                                 unsigned short* __restrict__ dst) {
    int idx = blockIdx.x * blockDim.x + threadIdx.x;
    if (idx >= HID_PAD * IN_PAD) return;
    int n = idx / IN_PAD;
    int k = idx - n * IN_PAD;
    dst[idx] = (k < IN_DIM && n < HID) ? f2bf(W1[(size_t)k * HID + n]) : 0;
}

// ---------------- GEMM1: bf16 128x128 tile (m97 2-barrier structure) ----------------

__global__ void k_gemm_bf(const unsigned short* __restrict__ A,
                          const unsigned short* __restrict__ Bt,
                          unsigned short* __restrict__ Cout,
                          int M, int N, int K) {
    __shared__ unsigned short ldsA[128 * 32];
    __shared__ unsigned short ldsB[128 * 32];

    const int tid = threadIdx.x;
    const int nbn = N >> 7;
    const int bm = blockIdx.x / nbn;
    const int bn = blockIdx.x - bm * nbn;

    const int wid = tid >> 6, lane = tid & 63;
    const int wr = wid >> 1, wc = wid & 1;
    const int lr = lane & 15, lg = lane >> 4;

    f32x4 acc[4][4] = {};

    const int r0 = tid >> 2, s0 = tid & 3;
    const unsigned short* Ag0 = A + ((size_t)bm * 128 + r0) * K + s0 * 8;
    const unsigned short* Ag1 = A + ((size_t)bm * 128 + 64 + r0) * K + s0 * 8;
    const unsigned short* Bg0 = Bt + ((size_t)bn * 128 + r0) * K + s0 * 8;
    const unsigned short* Bg1 = Bt + ((size_t)bn * 128 + 64 + r0) * K + s0 * 8;
    unsigned short* lA0 = ldsA + (size_t)(wid * 64) * 8;
    unsigned short* lA1 = ldsA + (size_t)(256 + wid * 64) * 8;
    unsigned short* lB0 = ldsB + (size_t)(wid * 64) * 8;
    unsigned short* lB1 = ldsB + (size_t)(256 + wid * 64) * 8;

    for (int kt = 0; kt < K; kt += 32) {
        __builtin_amdgcn_global_load_lds(
            (const __attribute__((address_space(1))) void*)(Ag0 + kt),
            (__attribute__((address_space(3))) void*)lA0, 16, 0, 0);
        __builtin_amdgcn_global_load_lds(
            (const __attribute__((address_space(1))) void*)(Ag1 + kt),
            (__attribute__((address_space(3))) void*)lA1, 16, 0, 0);
        __builtin_amdgcn_global_load_lds(
            (const __attribute__((address_space(1))) void*)(Bg0 + kt),
            (__attribute__((address_space(3))) void*)lB0, 16, 0, 0);
        __builtin_amdgcn_global_load_lds(
            (const __attribute__((address_space(1))) void*)(Bg1 + kt),
            (__attribute__((address_space(3))) void*)lB1, 16, 0, 0);
        __syncthreads();

        bf16x8 af[4], bfr[4];
#pragma unroll
        for (int i = 0; i < 4; i++) {
            af[i]  = *(const bf16x8*)&ldsA[((wr * 64 + i * 16 + lr) * 32) + lg * 8];
            bfr[i] = *(const bf16x8*)&ldsB[((wc * 64 + i * 16 + lr) * 32) + lg * 8];
        }
#pragma unroll
        for (int i = 0; i < 4; i++)
#pragma unroll
            for (int j = 0; j < 4; j++)
                acc[i][j] = __builtin_amdgcn_mfma_f32_16x16x32_bf16(af[i], bfr[j], acc[i][j], 0, 0, 0);
        __syncthreads();
    }

    const int row0 = bm * 128 + wr * 64;
    const int col0 = bn * 128 + wc * 64;
#pragma unroll
    for (int mi = 0; mi < 4; mi++) {
#pragma unroll
        for (int ni = 0; ni < 4; ni++) {
            int col = col0 + ni * 16 + lr;
#pragma unroll
            for (int j = 0; j < 4; j++) {
                int row = row0 + mi * 16 + lg * 4 + j;
                Cout[(size_t)row * N + col] = f2bf(acc[mi][ni][j]);
            }
        }
    }
}

// ---------------- GEMM2: bf16-A LDS (single reg-stage, load-early/write-late) ----------------
// h1 = relu(adj_fp32 * xwt^T + b1). 128x128 tile, 4 waves, 48 KB LDS (16K A + 2x16K B).
// Body t: [issue A(t+1)->regs] ds_read frags -> MFMA -> barrier1 ->
//         [cvt+ds_write A(t+1); issue B(t+2) gload_lds] -> lgkmcnt(0) -> barrier2.
// Wait correctness by FIFO: cvt's reg-dep wait on A(t+1) (newest) retires B(t+1)
// (older) => B always landed one body before use. No manual vmcnt in main loop.
// Swizzle (both-sides involution, slot^=(row&7)) on A and B; conflicts = 0 (R12).
// XCD swizzle: XCD x owns bm in [8x,8x+8) -> adj fetched ~once chip-wide.

__global__ __launch_bounds__(256, 3) void k_gemm2(const float* __restrict__ A,
                                                  const unsigned short* __restrict__ Bt,
                                                  const float* __restrict__ b1,
                                                  float* __restrict__ H) {
    __shared__ unsigned short ldsA[128 * BK2];        // 16 KB bf16 A
    __shared__ unsigned short ldsB[2][128 * BK2];     // 2 x 16 KB bf16 B

    const int tid = threadIdx.x;
    const int wg = blockIdx.x;                   // 512 blocks = 64 bm x 8 bn
    const int swz = (wg & 7) * 64 + (wg >> 3);   // bijective; XCD x owns bm in [8x,8x+8)
    const int bm = swz >> 3;
    const int bn = swz & 7;

    const int wid = tid >> 6, lane = tid & 63;
    const int wr = wid >> 1, wc = wid & 1;
    const int lr = lane & 15, lg = lane >> 4;

    f32x4 acc[4][4] = {};

    const float* Abase = A + ((size_t)bm * 128) * NN;
    const unsigned short* Bbase = Bt + ((size_t)bn * 128) * NN;

    const int bslot = (lane & 7) ^ (lane >> 3);      // B stage swizzle: row&7 = lane>>3
    const int arow = (lane >> 4);                    // A stage: row-in-chunk
    const int as   = lane & 15;                      // A stage: 16B col slot (fp32 x4)

    float4 arS[8];

    // ---- prologue ----
    // A(0) -> regs (oldest vmem)
#pragma unroll
    for (int q = 0; q < 8; q++) {
        const int c = wid * 8 + q;
        arS[q] = *(const float4*)(Abase + (size_t)(c * 4 + arow) * NN + as * 4);
    }
    // B(0), B(1) gloads (newer than A(0))
#pragma unroll
    for (int buf = 0; buf < 2; buf++) {
#pragma unroll
        for (int q = 0; q < 4; q++) {
            const int c = wid * 4 + q;
            const int r = c * 8 + (lane >> 3);
            __builtin_amdgcn_global_load_lds(
                (const __attribute__((address_space(1))) void*)
                    (Bbase + (size_t)r * NN + buf * 64 + bslot * 8),
                (__attribute__((address_space(3))) void*)(&ldsB[buf][0] + c * 512),
                16, 0, 0);
        }
    }
    // cvt+write A(0) (reg-dep waits A(0); B(0),B(1) stay in flight)
#pragma unroll
    for (int q = 0; q < 8; q++) {
        const int c = wid * 8 + q;
        const int r = c * 4 + arow;
        uint2 pk;
        pk.x = cvt_pk_bf16(arS[q].x, arS[q].y);
        pk.y = cvt_pk_bf16(arS[q].z, arS[q].w);
        *(uint2*)&ldsA[r * 64 + (((as >> 1) ^ (r & 7)) << 3) + (as & 1) * 4] = pk;
    }
    asm volatile("s_waitcnt vmcnt(4) lgkmcnt(0)" ::: "memory");   // B(0) landed; B(1) flies
    __builtin_amdgcn_sched_barrier(0);
    __builtin_amdgcn_s_barrier();
    __builtin_amdgcn_sched_barrier(0);

    // ---- main loop ----
    for (int t = 0; t < NT2; ++t) {
        const int kt = t * BK2;

        // ph1: issue A(t+1) early (flies across ds_read + MFMA)
        if (t + 1 < NT2) {
#pragma unroll
            for (int q = 0; q < 8; q++) {
                const int c = wid * 8 + q;
                arS[q] = *(const float4*)(Abase + (size_t)(c * 4 + arow) * NN + kt + 64 + as * 4);
            }
        }
        __builtin_amdgcn_sched_barrier(0);

        // fragments + MFMA
        {
            const unsigned short* Bb = &ldsB[t & 1][0];
            bf16x8 af[4], bfr[4];
#pragma unroll
            for (int kk = 0; kk < 2; kk++) {
#pragma unroll
                for (int i = 0; i < 4; i++) {
                    const int r = wr * 64 + i * 16 + lr;
                    const int p = (kk * 4 + lg) ^ (r & 7);
                    af[i] = *(const bf16x8*)&ldsA[r * 64 + p * 8];
                }
#pragma unroll
                for (int j = 0; j < 4; j++) {
                    const int r = wc * 64 + j * 16 + lr;
                    const int p = (kk * 4 + lg) ^ (r & 7);
                    bfr[j] = *(const bf16x8*)&Bb[r * 64 + p * 8];
                }
                __builtin_amdgcn_s_setprio(1);
#pragma unroll
                for (int i = 0; i < 4; i++)
#pragma unroll
                    for (int j = 0; j < 4; j++)
                        acc[i][j] = __builtin_amdgcn_mfma_f32_16x16x32_bf16(af[i], bfr[j], acc[i][j], 0, 0, 0);
                __builtin_amdgcn_s_setprio(0);
            }
        }

        __builtin_amdgcn_s_barrier();          // barrier1: all waves done reading
        __builtin_amdgcn_sched_barrier(0);

        // ph3: cvt+write A(t+1); issue B(t+2)
        if (t + 1 < NT2) {
#pragma unroll
            for (int q = 0; q < 8; q++) {
                const int c = wid * 8 + q;
                const int r = c * 4 + arow;
                uint2 pk;
                pk.x = cvt_pk_bf16(arS[q].x, arS[q].y);   // reg-dep wait drains A(t+1) + B(t+1)
                pk.y = cvt_pk_bf16(arS[q].z, arS[q].w);
                *(uint2*)&ldsA[r * 64 + (((as >> 1) ^ (r & 7)) << 3) + (as & 1) * 4] = pk;
            }
            if (t + 2 < NT2) {
#pragma unroll
                for (int q = 0; q < 4; q++) {
                    const int c = wid * 4 + q;
                    const int r = c * 8 + (lane >> 3);
                    __builtin_amdgcn_global_load_lds(
                        (const __attribute__((address_space(1))) void*)
                            (Bbase + (size_t)r * NN + kt + 128 + bslot * 8),
                        (__attribute__((address_space(3))) void*)(&ldsB[t & 1][0] + c * 512),
                        16, 0, 0);
                }
            }
            asm volatile("s_waitcnt lgkmcnt(0)" ::: "memory");
            __builtin_amdgcn_sched_barrier(0);
        }
        __builtin_amdgcn_s_barrier();          // barrier2: ldsA/ldsB ready for next body
        __builtin_amdgcn_sched_barrier(0);
    }

    // ---- epilogue: bias + relu fused, fp32 store ----
    const int row0 = bm * 128 + wr * 64;
    const int col0 = bn * 128 + wc * 64;
#pragma unroll
    for (int mi = 0; mi < 4; mi++) {
#pragma unroll
        for (int ni = 0; ni < 4; ni++) {
            int col = col0 + ni * 16 + lr;
            float b = (col < HID) ? b1[col] : 0.f;
#pragma unroll
            for (int j = 0; j < 4; j++) {
                int row = row0 + mi * 16 + lg * 4 + j;
                float v = acc[mi][ni][j] + b;
                v = v > 0.f ? v : 0.f;
                H[(size_t)row * HID_PAD + col] = v;
            }
        }
    }
}

// ---------------- LayerNorm + head ----------------
__global__ __launch_bounds__(256) void k_ln_head(const float* __restrict__ h1p,
                                                 const float* __restrict__ gamma,
                                                 const float* __restrict__ beta,
                                                 const float* __restrict__ Wm,
                                                 const float* __restrict__ bm,
                                                 float* __restrict__ out) {
    const int row = blockIdx.x;
    const int t = threadIdx.x;
    const float* hr = h1p + (size_t)row * HID_PAD;

    float v[4];
    float s = 0.f, ss = 0.f;
#pragma unroll
    for (int i = 0; i < 4; i++) {
        int ix = t + i * 256;
        float x = (ix < HID) ? hr[ix] : 0.f;
        v[i] = x; s += x; ss += x * x;
    }
#pragma unroll
    for (int o = 32; o > 0; o >>= 1) { s += __shfl_down(s, o); ss += __shfl_down(ss, o); }

    __shared__ float rs[8], rss[8];
    const int wid = t >> 6, lane = t & 63;
    if (lane == 0) { rs[wid] = s; rss[wid] = ss; }
    __syncthreads();
    if (t == 0) {
        float a = 0.f, b = 0.f;
        for (int w = 0; w < 4; w++) { a += rs[w]; b += rss[w]; }
        rs[4] = a; rss[4] = b;
    }
    __syncthreads();
    const float mean = rs[4] * (1.0f / HID);
    const float var = rss[4] * (1.0f / HID) - mean * mean;
    const float rstd = rsqrtf(var + EPS);

    float q0 = 0.f, q1 = 0.f, q2 = 0.f, q3 = 0.f;
#pragma unroll
    for (int i = 0; i < 4; i++) {
        int ix = t + i * 256;
        if (ix < HID) {
            float hn = (v[i] - mean) * rstd * gamma[ix] + beta[ix];
            const float* w = Wm + (size_t)ix * 4;
            q0 += hn * w[0]; q1 += hn * w[1]; q2 += hn * w[2]; q3 += hn * w[3];
        }
    }
#pragma unroll
    for (int o = 32; o > 0; o >>= 1) {
        q0 += __shfl_down(q0, o); q1 += __shfl_down(q1, o);
        q2 += __shfl_down(q2, o); q3 += __shfl_down(q3, o);
    }
    __shared__ float rp[4][4];
    if (lane == 0) { rp[wid][0] = q0; rp[wid][1] = q1; rp[wid][2] = q2; rp[wid][3] = q3; }
    __syncthreads();
    if (t < 4) {
        float a = rp[0][t] + rp[1][t] + rp[2][t] + rp[3][t] + bm[t];
        out[(size_t)row * 4 + t] = a;
    }
}

// ---------------- launcher ----------------
extern "C" void kernel_launch(void* const* d_in, const int* in_sizes, int n_in,
                              void* d_out, int out_size, void* d_ws, size_t ws_size,
                              hipStream_t stream) {
    const float* adj      = (const float*)d_in[0];
    const float* features = (const float*)d_in[1];
    const float* W1       = (const float*)d_in[2];
    const float* b1       = (const float*)d_in[3];
    const float* gamma    = (const float*)d_in[4];
    const float* beta     = (const float*)d_in[5];
    const float* Wm       = (const float*)d_in[6];
    const float* bm       = (const float*)d_in[7];
    float* out = (float*)d_out;

    uint8_t* ws = (uint8_t*)d_ws;
    unsigned short* feat_p = (unsigned short*)ws;                 //  5,767,168 B
    unsigned short* w1t    = (unsigned short*)(ws + 5767168);     //    720,896 B
    unsigned short* xwt    = (unsigned short*)(ws + 6488064);     // 16,777,216 B
    float*          h1     = (float*)(ws + 23265280);             // 33,554,432 B (~57 MB total)

    k_cvt_feat<<<(NN * IN_PAD + 255) / 256, 256, 0, stream>>>(features, feat_p);
    k_cvt_w1t<<<(HID_PAD * IN_PAD + 255) / 256, 256, 0, stream>>>(W1, w1t);

    // GEMM1: xwt[1024][8192] = w1t * feat_p^T  (bf16 out)
    k_gemm_bf<<<(HID_PAD / 128) * (NN / 128), 256, 0, stream>>>(
        w1t, feat_p, xwt, HID_PAD, NN, IN_PAD);

    // GEMM2: h1 = relu(adj * xwt^T + b1); bf16-A single-reg-stage, dbuf B, BK=64
    k_gemm2<<<(NN / 128) * (HID_PAD / 128), 256, 0, stream>>>(adj, xwt, b1, h1);

    k_ln_head<<<NN, 256, 0, stream>>>(h1, gamma, beta, Wm, bm, out);
}